// Round 3
// baseline (383.860 us; speedup 1.0000x reference)
//
#include <hip/hip_runtime.h>

#define TPB 256
#define RED_NB 2048

// Gaussian kernel, sigma=1.1, ksize=5 (precomputed, normalized)
#define K0 0.0707663f
#define K1 0.2444606f
#define K2 0.3695462f

#define TS 16          // fused-tile output edge
#define IMG_E (TS + 6) // 22: image tile extent (halo 3)
#define GM_E  (TS + 4) // 20: gradmag tile extent (halo 2)

typedef float f4 __attribute__((ext_vector_type(4)));

__device__ __forceinline__ f4 ld4(const float* __restrict__ p) { return *(const f4*)p; }

// reflect index (no edge repeat): j<0 -> -j, j>=n -> 2n-2-j
__device__ __forceinline__ int rref(int i, int n) {
    return i < 0 ? -i : (i >= n ? 2 * n - 2 - i : i);
}

// -------- trilinear resize, align_corners --------
__global__ void resize3d_kernel(const float* __restrict__ in, float* __restrict__ out,
                                int BC, int n, int m, float ratio) {
    long total = (long)BC * m * m * m;
    long idx = (long)blockIdx.x * blockDim.x + threadIdx.x;
    if (idx >= total) return;
    int z = (int)(idx % m); long r = idx / m;
    int y = (int)(r % m);   r /= m;
    int x = (int)(r % m);   int bc = (int)(r / m);

    float cx = (float)x * ratio, cy = (float)y * ratio, cz = (float)z * ratio;
    int x0 = min((int)cx, n - 1), y0 = min((int)cy, n - 1), z0 = min((int)cz, n - 1);
    float wx = cx - (float)x0, wy = cy - (float)y0, wz = cz - (float)z0;
    int x1 = min(x0 + 1, n - 1), y1 = min(y0 + 1, n - 1), z1 = min(z0 + 1, n - 1);

    const float* p = in + (long)bc * n * n * n;
    long sx = (long)n * n;
#define AT(xi, yi, zi) p[(long)(xi) * sx + (long)(yi) * n + (zi)]
    float c00 = AT(x0, y0, z0) * (1.f - wz) + AT(x0, y0, z1) * wz;
    float c01 = AT(x0, y1, z0) * (1.f - wz) + AT(x0, y1, z1) * wz;
    float c10 = AT(x1, y0, z0) * (1.f - wz) + AT(x1, y0, z1) * wz;
    float c11 = AT(x1, y1, z0) * (1.f - wz) + AT(x1, y1, z1) * wz;
#undef AT
    float c0 = c00 * (1.f - wy) + c01 * wy;
    float c1 = c10 * (1.f - wy) + c11 * wy;
    out[idx] = c0 * (1.f - wx) + c1 * wx;
}

// -------- fused gradmag + 3-axis Gaussian blur (one pass: image -> smoothed ig) --------
__global__ __launch_bounds__(TPB)
void igchain_kernel(const float* __restrict__ img, float* __restrict__ ig,
                    int n, int nt) {
    __shared__ float A[IMG_E * IMG_E * IMG_E]; // image tile, then blur-x result
    __shared__ float Bs[GM_E * GM_E * GM_E];   // gradmag, then blur-y result

    int bid = blockIdx.x;
    int tz = bid % nt; int r = bid / nt;
    int ty = r % nt;   r /= nt;
    int tx = r % nt;   int b = r / nt;
    int tsx = tx * TS, tsy = ty * TS, tsz = tz * TS;
    long n2 = (long)n * n, n3 = n2 * n;
    const float* ib = img + (long)b * n3;
    int tid = threadIdx.x;
    const float K[5] = {K0, K1, K2, K1, K0};

    // phase 0: cooperative load of image region [ts-3, ts+TS+3), clamped
    for (int i = tid; i < IMG_E * IMG_E * IMG_E; i += TPB) {
        int lz = i % IMG_E; int t2 = i / IMG_E;
        int ly = t2 % IMG_E; int lx = t2 / IMG_E;
        int gx = min(max(tsx - 3 + lx, 0), n - 1);
        int gy = min(max(tsy - 3 + ly, 0), n - 1);
        int gz = min(max(tsz - 3 + lz, 0), n - 1);
        A[i] = ib[(long)gx * n2 + (long)gy * n + gz];
    }
    __syncthreads();

    // phase 1: gradmag on [ts-2, ts+TS+2) (jnp.gradient edge logic), guarded
    for (int i = tid; i < GM_E * GM_E * GM_E; i += TPB) {
        int lz = i % GM_E; int t2 = i / GM_E;
        int ly = t2 % GM_E; int lx = t2 / GM_E;
        int gx = tsx - 2 + lx, gy = tsy - 2 + ly, gz = tsz - 2 + lz;
        float v = 0.f;
        if (gx >= 0 && gx < n && gy >= 0 && gy < n && gz >= 0 && gz < n) {
            int ax = lx + 1, ay = ly + 1, az = lz + 1;
#define AA(X, Y, Z) A[((X) * IMG_E + (Y)) * IMG_E + (Z)]
            float dx = (gx == 0) ? AA(ax + 1, ay, az) - AA(ax, ay, az)
                     : (gx == n - 1) ? AA(ax, ay, az) - AA(ax - 1, ay, az)
                     : 0.5f * (AA(ax + 1, ay, az) - AA(ax - 1, ay, az));
            float dy = (gy == 0) ? AA(ax, ay + 1, az) - AA(ax, ay, az)
                     : (gy == n - 1) ? AA(ax, ay, az) - AA(ax, ay - 1, az)
                     : 0.5f * (AA(ax, ay + 1, az) - AA(ax, ay - 1, az));
            float dz = (gz == 0) ? AA(ax, ay, az + 1) - AA(ax, ay, az)
                     : (gz == n - 1) ? AA(ax, ay, az) - AA(ax, ay, az - 1)
                     : 0.5f * (AA(ax, ay, az + 1) - AA(ax, ay, az - 1));
#undef AA
            v = sqrtf(dx * dx + dy * dy + dz * dz);
        }
        Bs[i] = v;
    }
    __syncthreads();

    // phase 2: blur along x -> A laid out [TS][GM_E][GM_E]
    for (int i = tid; i < TS * GM_E * GM_E; i += TPB) {
        int lz = i % GM_E; int t2 = i / GM_E;
        int ly = t2 % GM_E; int lx = t2 / GM_E;
        int gx = tsx + lx, gy = tsy - 2 + ly, gz = tsz - 2 + lz;
        float acc = 0.f;
        if (gx < n && gy >= 0 && gy < n && gz >= 0 && gz < n) {
#pragma unroll
            for (int t = 0; t < 5; ++t) {
                int q = rref(gx + t - 2, n);
                int lq = q - (tsx - 2);
                acc += K[t] * Bs[(lq * GM_E + ly) * GM_E + lz];
            }
        }
        A[i] = acc;
    }
    __syncthreads();

    // phase 3: blur along y -> Bs laid out [TS][TS][GM_E]
    for (int i = tid; i < TS * TS * GM_E; i += TPB) {
        int lz = i % GM_E; int t2 = i / GM_E;
        int ly = t2 % TS; int lx = t2 / TS;
        int gx = tsx + lx, gy = tsy + ly, gz = tsz - 2 + lz;
        float acc = 0.f;
        if (gx < n && gy < n && gz >= 0 && gz < n) {
#pragma unroll
            for (int t = 0; t < 5; ++t) {
                int q = rref(gy + t - 2, n);
                int lq = q - (tsy - 2);
                acc += K[t] * A[(lx * GM_E + lq) * GM_E + lz];
            }
        }
        Bs[(lx * TS + ly) * GM_E + lz] = acc;
    }
    __syncthreads();

    // phase 4: blur along z, store to global
    for (int i = tid; i < TS * TS * TS; i += TPB) {
        int lz = i % TS; int t2 = i / TS;
        int ly = t2 % TS; int lx = t2 / TS;
        int gx = tsx + lx, gy = tsy + ly, gz = tsz + lz;
        if (gx < n && gy < n && gz < n) {
            float acc = 0.f;
#pragma unroll
            for (int t = 0; t < 5; ++t) {
                int q = rref(gz + t - 2, n);
                int lq = q - (tsz - 2);
                acc += K[t] * Bs[(lx * TS + ly) * GM_E + lq];
            }
            ig[(long)b * n3 + (long)gx * n2 + (long)gy * n + gz] = acc;
        }
    }
}

// -------- Lame strain energy, f4 over z, block-reduced --------
__global__ void energy_v4(const float* __restrict__ def, const float* __restrict__ ig,
                          float* __restrict__ partial, int B, int n) {
    int nz4 = n >> 2;
    long n2 = (long)n * n, n3 = n2 * n;
    long total = (long)B * n * n * nz4;
    float lsum = 0.f;
    for (long idx = (long)blockIdx.x * blockDim.x + threadIdx.x; idx < total;
         idx += (long)gridDim.x * blockDim.x) {
        int z4 = (int)(idx % nz4); long r = idx / nz4;
        int y = (int)(r % n); r /= n;
        int x = (int)(r % n); int b = (int)(r / n);
        int z = z4 * 4;

        int xm = max(x - 1, 0), xp = min(x + 1, n - 1);
        int ym = max(y - 1, 0), yp = min(y + 1, n - 1);
        float hx = (x == 0 || x == n - 1) ? 1.f : 0.5f;
        float hy = (y == 0 || y == n - 1) ? 1.f : 0.5f;

        const float* base = def + (long)b * 3 * n3;
        long sp = (long)x * n2 + (long)y * n + z;

        f4 CC[3], CP[3], CN[3], RXP[3], RXM[3], RYP[3], RYM[3];
#pragma unroll
        for (int c = 0; c < 3; ++c) {
            const float* rc = base + (long)c * n3 + sp;
            CC[c] = ld4(rc);
            CP[c] = (z > 0) ? ld4(rc - 4) : CC[c];
            CN[c] = (z + 4 < n) ? ld4(rc + 4) : CC[c];
            RXP[c] = ld4(base + (long)c * n3 + (long)xp * n2 + (long)y * n + z);
            RXM[c] = ld4(base + (long)c * n3 + (long)xm * n2 + (long)y * n + z);
            RYP[c] = ld4(base + (long)c * n3 + (long)x * n2 + (long)yp * n + z);
            RYM[c] = ld4(base + (long)c * n3 + (long)x * n2 + (long)ym * n + z);
        }
        f4 igv4 = ld4(ig + (long)b * n3 + sp);

#pragma unroll
        for (int j = 0; j < 4; ++j) {
            int gz = z + j;
            float dX[3], dY[3], dZ[3];
#pragma unroll
            for (int c = 0; c < 3; ++c) {
                float cc = CC[c][j];
                float zmv = (j == 0) ? CP[c][3] : CC[c][(j == 0) ? 0 : j - 1];
                float zpv = (j == 3) ? CN[c][0] : CC[c][(j == 3) ? 3 : j + 1];
                dZ[c] = (gz == 0) ? (zpv - cc)
                                  : ((gz == n - 1) ? (cc - zmv) : 0.5f * (zpv - zmv));
                dX[c] = hx * (RXP[c][j] - RXM[c][j]);
                dY[c] = hy * (RYP[c][j] - RYM[c][j]);
            }
            float igv = igv4[j];
            float lam = fminf(fmaxf(1.0f + 2.0f * igv, 0.1f), 10.0f);
            float mu  = fminf(fmaxf(0.5f + 1.0f * igv, 0.1f), 10.0f);
            float wt  = 1.0f + 5.0f * igv;

            float Exx = dX[0], Eyy = dY[1], Ezz = dZ[2];
            float Exy = 0.5f * (dY[0] + dX[1]);
            float Exz = 0.5f * (dZ[0] + dX[2]);
            float Eyz = 0.5f * (dZ[1] + dY[2]);
            float tr = Exx + Eyy + Ezz;
            float e = 0.5f * lam * tr * tr +
                      mu * (Exx * Exx + Eyy * Eyy + Ezz * Ezz +
                            2.0f * (Exy * Exy + Exz * Exz + Eyz * Eyz));
            lsum += wt * e;
        }
    }
    __shared__ float sm[TPB];
    sm[threadIdx.x] = lsum;
    __syncthreads();
    for (int s = TPB / 2; s > 0; s >>= 1) {
        if (threadIdx.x < s) sm[threadIdx.x] += sm[threadIdx.x + s];
        __syncthreads();
    }
    if (threadIdx.x == 0) partial[blockIdx.x] = sm[0];
}

// -------- combine 3 scale partials + Jacobian penalty -> out[0] --------
__global__ void finalize_kernel(const float* __restrict__ partial,
                                const float* __restrict__ def, float* __restrict__ out) {
    __shared__ float sm[TPB];
    const float wts[3] = {1.0f, 0.5f, 0.25f};
    const float invcnt[3] = {1.0f / (2.0f * 160 * 160 * 160),
                             1.0f / (2.0f * 80 * 80 * 80),
                             1.0f / (2.0f * 40 * 40 * 40)};
    float acc = 0.f;
    for (int s = 0; s < 3; ++s) {
        float local = 0.f;
        for (int i = threadIdx.x; i < RED_NB; i += TPB) local += partial[s * RED_NB + i];
        acc += wts[s] * invcnt[s] * local;
    }
    sm[threadIdx.x] = acc;
    __syncthreads();
    for (int s = TPB / 2; s > 0; s >>= 1) {
        if (threadIdx.x < s) sm[threadIdx.x] += sm[threadIdx.x + s];
        __syncthreads();
    }
    if (threadIdx.x == 0) {
        float jac = 0.f;
        const int n = 160;
        long n3 = (long)n * n * n;
        long ctr = ((long)80 * n + 80) * n + 80;
        for (int b = 0; b < 2; ++b) {
            const float* p = def + (long)b * 3 * n3;
            float J[3][3];
            for (int c = 0; c < 3; ++c) {
                const float* q = p + (long)c * n3 + ctr;
                J[c][0] = 0.5f * (q[(long)n * n] - q[-(long)n * n]);
                J[c][1] = 0.5f * (q[n] - q[-n]);
                J[c][2] = 0.5f * (q[1] - q[-1]);
            }
            float det = J[0][0] * (J[1][1] * J[2][2] - J[1][2] * J[2][1])
                      - J[0][1] * (J[1][0] * J[2][2] - J[1][2] * J[2][0])
                      + J[0][2] * (J[1][0] * J[2][1] - J[1][1] * J[2][0]);
            jac += fmaxf(-det, 0.f);
        }
        jac *= 0.5f; // mean over B=2
        out[0] = sm[0] + 0.1f * jac;
    }
}

extern "C" void kernel_launch(void* const* d_in, const int* in_sizes, int n_in,
                              void* d_out, int out_size, void* d_ws, size_t ws_size,
                              hipStream_t stream) {
    const float* D = (const float*)d_in[0];  // (2,3,160,160,160)
    const float* I = (const float*)d_in[1];  // (2,1,160,160,160)
    float* out = (float*)d_out;
    float* ws = (float*)d_ws;

    const int B = 2;
    const long S0 = (long)B * 160 * 160 * 160;
    const long S1 = (long)B * 80 * 80 * 80;
    const long S2 = (long)B * 40 * 40 * 40;

    // disjoint workspace layout (no aliasing)
    float* partials = ws;                 // 3 * RED_NB
    float* ig0 = partials + 3 * RED_NB;   // S0
    float* ds1 = ig0 + S0;                // 3*S1
    float* is1 = ds1 + 3 * S1;            // S1
    float* ig1 = is1 + S1;                // S1
    float* ds2 = ig1 + S1;                // 3*S2
    float* is2 = ds2 + 3 * S2;            // S2
    float* ig2 = is2 + S2;                // S2

    // ---- resizes (D, I each read once back-to-back; 2nd pass mostly L3) ----
    {
        const int nin = 160;
        float r1 = (float)((nin - 1.0) / (80 - 1.0));
        float r2 = (float)((nin - 1.0) / (40 - 1.0));
        long totD1 = 3 * S1, totD2 = 3 * S2;
        resize3d_kernel<<<(int)((totD1 + TPB - 1) / TPB), TPB, 0, stream>>>(D, ds1, B * 3, nin, 80, r1);
        resize3d_kernel<<<(int)((totD2 + TPB - 1) / TPB), TPB, 0, stream>>>(D, ds2, B * 3, nin, 40, r2);
        resize3d_kernel<<<(int)((S1 + TPB - 1) / TPB), TPB, 0, stream>>>(I, is1, B, nin, 80, r1);
        resize3d_kernel<<<(int)((S2 + TPB - 1) / TPB), TPB, 0, stream>>>(I, is2, B, nin, 40, r2);
    }

    // ---- fused ig chains (gradmag + 3 blurs in one pass each) ----
    {
        int nt0 = (160 + TS - 1) / TS;  // 10
        int nt1 = (80 + TS - 1) / TS;   // 5
        int nt2 = (40 + TS - 1) / TS;   // 3
        igchain_kernel<<<B * nt0 * nt0 * nt0, TPB, 0, stream>>>(I,   ig0, 160, nt0);
        igchain_kernel<<<B * nt1 * nt1 * nt1, TPB, 0, stream>>>(is1, ig1, 80,  nt1);
        igchain_kernel<<<B * nt2 * nt2 * nt2, TPB, 0, stream>>>(is2, ig2, 40,  nt2);
    }

    // ---- energies ----
    energy_v4<<<RED_NB, TPB, 0, stream>>>(D,   ig0, partials + 0 * RED_NB, B, 160);
    energy_v4<<<RED_NB, TPB, 0, stream>>>(ds1, ig1, partials + 1 * RED_NB, B, 80);
    energy_v4<<<RED_NB, TPB, 0, stream>>>(ds2, ig2, partials + 2 * RED_NB, B, 40);

    finalize_kernel<<<1, TPB, 0, stream>>>(partials, D, out);
}

// Round 4
// 211.782 us; speedup vs baseline: 1.8125x; 1.8125x over previous
//
#include <hip/hip_runtime.h>

#define TPB 256
#define RED_NB 2048

// Gaussian kernel, sigma=1.1, ksize=5 (precomputed, normalized)
#define K0 0.0707663f
#define K1 0.2444606f
#define K2 0.3695462f

typedef float f4 __attribute__((ext_vector_type(4)));

__device__ __forceinline__ f4 ld4(const float* __restrict__ p) { return *(const f4*)p; }

// reflect index (no edge repeat): j<0 -> -j, j>=n -> 2n-2-j
__device__ __forceinline__ int rref(int i, int n) {
    return i < 0 ? -i : (i >= n ? 2 * n - 2 - i : i);
}

// -------- trilinear resize, align_corners; compile-time sizes --------
template <int NIN, int M>
__global__ void resize3d_kernel(const float* __restrict__ in, float* __restrict__ out,
                                int BC) {
    constexpr float ratio = (float)((NIN - 1.0) / (M - 1.0));
    long total = (long)BC * M * M * M;
    long idx = (long)blockIdx.x * blockDim.x + threadIdx.x;
    if (idx >= total) return;
    int z = (int)(idx % M); long r = idx / M;
    int y = (int)(r % M);   r /= M;
    int x = (int)(r % M);   int bc = (int)(r / M);

    float cx = (float)x * ratio, cy = (float)y * ratio, cz = (float)z * ratio;
    int x0 = min((int)cx, NIN - 1), y0 = min((int)cy, NIN - 1), z0 = min((int)cz, NIN - 1);
    float wx = cx - (float)x0, wy = cy - (float)y0, wz = cz - (float)z0;
    int x1 = min(x0 + 1, NIN - 1), y1 = min(y0 + 1, NIN - 1), z1 = min(z0 + 1, NIN - 1);

    const float* p = in + (long)bc * NIN * NIN * NIN;
    constexpr long sx = (long)NIN * NIN;
#define AT(xi, yi, zi) p[(long)(xi) * sx + (long)(yi) * NIN + (zi)]
    float c00 = AT(x0, y0, z0) * (1.f - wz) + AT(x0, y0, z1) * wz;
    float c01 = AT(x0, y1, z0) * (1.f - wz) + AT(x0, y1, z1) * wz;
    float c10 = AT(x1, y0, z0) * (1.f - wz) + AT(x1, y0, z1) * wz;
    float c11 = AT(x1, y1, z0) * (1.f - wz) + AT(x1, y1, z1) * wz;
#undef AT
    float c0 = c00 * (1.f - wy) + c01 * wy;
    float c1 = c10 * (1.f - wy) + c11 * wy;
    out[idx] = c0 * (1.f - wx) + c1 * wx;
}

// -------- gradient magnitude, f4 over z --------
template <int N>
__global__ void gradmag_v4(const float* __restrict__ img, float* __restrict__ g, int B) {
    constexpr int NZ4 = N / 4;
    constexpr long n2 = (long)N * N, n3 = n2 * N;
    long total = (long)B * N * N * NZ4;
    long idx = (long)blockIdx.x * blockDim.x + threadIdx.x;
    if (idx >= total) return;
    int z4 = (int)(idx % NZ4); long r = idx / NZ4;
    int y = (int)(r % N); r /= N;
    int x = (int)(r % N); int b = (int)(r / N);
    int z = z4 * 4;

    const float* base = img + (long)b * n3;
    const float* rowc = base + (long)x * n2 + (long)y * N;
    f4 cur = ld4(rowc + z);
    f4 prev = (z > 0) ? ld4(rowc + z - 4) : cur;
    f4 next = (z + 4 < N) ? ld4(rowc + z + 4) : cur;

    int xm = max(x - 1, 0), xp = min(x + 1, N - 1);
    int ym = max(y - 1, 0), yp = min(y + 1, N - 1);
    float hx = (x == 0 || x == N - 1) ? 1.f : 0.5f;
    float hy = (y == 0 || y == N - 1) ? 1.f : 0.5f;
    f4 rxp = ld4(base + (long)xp * n2 + (long)y * N + z);
    f4 rxm = ld4(base + (long)xm * n2 + (long)y * N + z);
    f4 ryp = ld4(base + (long)x * n2 + (long)yp * N + z);
    f4 rym = ld4(base + (long)x * n2 + (long)ym * N + z);

    f4 outv;
#pragma unroll
    for (int j = 0; j < 4; ++j) {
        float c = cur[j];
        float zmv = (j == 0) ? prev[3] : cur[(j == 0) ? 0 : j - 1];
        float zpv = (j == 3) ? next[0] : cur[(j == 3) ? 3 : j + 1];
        int gz = z + j;
        float dz = (gz == 0) ? (zpv - c) : ((gz == N - 1) ? (c - zmv) : 0.5f * (zpv - zmv));
        float dx = hx * (rxp[j] - rxm[j]);
        float dy = hy * (ryp[j] - rym[j]);
        outv[j] = sqrtf(dx * dx + dy * dy + dz * dz);
    }
    *(f4*)(g + (long)b * n3 + (long)x * n2 + (long)y * N + z) = outv;
}

// -------- blur along x (AXIS=0) or y (AXIS=1), f4 over z --------
template <int N, int AXIS>
__global__ void blur_xy_v4(const float* __restrict__ in, float* __restrict__ out, int B) {
    constexpr int NZ4 = N / 4;
    constexpr long n2 = (long)N * N, n3 = n2 * N;
    long total = (long)B * N * N * NZ4;
    long idx = (long)blockIdx.x * blockDim.x + threadIdx.x;
    if (idx >= total) return;
    int z4 = (int)(idx % NZ4); long r = idx / NZ4;
    int y = (int)(r % N); r /= N;
    int x = (int)(r % N); int b = (int)(r / N);
    int z = z4 * 4;

    int pos; long s; long off_fixed;
    if (AXIS == 0) { pos = x; s = n2; off_fixed = (long)b * n3 + (long)y * N + z; }
    else           { pos = y; s = N;  off_fixed = (long)b * n3 + (long)x * n2 + z; }

    const float K[5] = {K0, K1, K2, K1, K0};
    f4 acc = {0.f, 0.f, 0.f, 0.f};
#pragma unroll
    for (int t = 0; t < 5; ++t) {
        int q = rref(pos + t - 2, N);
        f4 v = ld4(in + off_fixed + (long)q * s);
        acc += K[t] * v;
    }
    *(f4*)(out + (long)b * n3 + (long)x * n2 + (long)y * N + z) = acc;
}

// -------- blur along z, f4, reflect boundaries --------
template <int N>
__global__ void blur_z_v4(const float* __restrict__ in, float* __restrict__ out, int B) {
    constexpr int NZ4 = N / 4;
    constexpr long n2 = (long)N * N, n3 = n2 * N;
    long total = (long)B * N * N * NZ4;
    long idx = (long)blockIdx.x * blockDim.x + threadIdx.x;
    if (idx >= total) return;
    int z4 = (int)(idx % NZ4); long r = idx / NZ4;
    int y = (int)(r % N); r /= N;
    int x = (int)(r % N); int b = (int)(r / N);
    int z = z4 * 4;

    const float* rowc = in + (long)b * n3 + (long)x * n2 + (long)y * N;
    f4 cur = ld4(rowc + z);
    f4 prev, next;
    if (z >= 4) prev = ld4(rowc + z - 4);
    else { prev[0] = rowc[4]; prev[1] = rowc[3]; prev[2] = rowc[2]; prev[3] = rowc[1]; }
    if (z + 8 <= N) next = ld4(rowc + z + 4);
    else { next[0] = rowc[N - 2]; next[1] = rowc[N - 3]; next[2] = rowc[N - 4]; next[3] = rowc[N - 5]; }

    float w[12];
#pragma unroll
    for (int i = 0; i < 4; ++i) { w[i] = prev[i]; w[4 + i] = cur[i]; w[8 + i] = next[i]; }

    f4 outv;
#pragma unroll
    for (int j = 0; j < 4; ++j)
        outv[j] = K0 * w[2 + j] + K1 * w[3 + j] + K2 * w[4 + j] + K1 * w[5 + j] + K0 * w[6 + j];

    *(f4*)(out + (long)b * n3 + (long)x * n2 + (long)y * N + z) = outv;
}

// -------- Lame strain energy, f4 over z, block-reduced --------
template <int N>
__global__ void energy_v4(const float* __restrict__ def, const float* __restrict__ ig,
                          float* __restrict__ partial, int B) {
    constexpr int NZ4 = N / 4;
    constexpr long n2 = (long)N * N, n3 = n2 * N;
    long total = (long)B * N * N * NZ4;
    float lsum = 0.f;
    for (long idx = (long)blockIdx.x * blockDim.x + threadIdx.x; idx < total;
         idx += (long)gridDim.x * blockDim.x) {
        int z4 = (int)(idx % NZ4); long r = idx / NZ4;
        int y = (int)(r % N); r /= N;
        int x = (int)(r % N); int b = (int)(r / N);
        int z = z4 * 4;

        int xm = max(x - 1, 0), xp = min(x + 1, N - 1);
        int ym = max(y - 1, 0), yp = min(y + 1, N - 1);
        float hx = (x == 0 || x == N - 1) ? 1.f : 0.5f;
        float hy = (y == 0 || y == N - 1) ? 1.f : 0.5f;

        const float* base = def + (long)b * 3 * n3;
        long sp = (long)x * n2 + (long)y * N + z;

        f4 CC[3], CP[3], CN[3], RXP[3], RXM[3], RYP[3], RYM[3];
#pragma unroll
        for (int c = 0; c < 3; ++c) {
            const float* rc = base + (long)c * n3 + sp;
            CC[c] = ld4(rc);
            CP[c] = (z > 0) ? ld4(rc - 4) : CC[c];
            CN[c] = (z + 4 < N) ? ld4(rc + 4) : CC[c];
            RXP[c] = ld4(base + (long)c * n3 + (long)xp * n2 + (long)y * N + z);
            RXM[c] = ld4(base + (long)c * n3 + (long)xm * n2 + (long)y * N + z);
            RYP[c] = ld4(base + (long)c * n3 + (long)x * n2 + (long)yp * N + z);
            RYM[c] = ld4(base + (long)c * n3 + (long)x * n2 + (long)ym * N + z);
        }
        f4 igv4 = ld4(ig + (long)b * n3 + sp);

#pragma unroll
        for (int j = 0; j < 4; ++j) {
            int gz = z + j;
            float dX[3], dY[3], dZ[3];
#pragma unroll
            for (int c = 0; c < 3; ++c) {
                float cc = CC[c][j];
                float zmv = (j == 0) ? CP[c][3] : CC[c][(j == 0) ? 0 : j - 1];
                float zpv = (j == 3) ? CN[c][0] : CC[c][(j == 3) ? 3 : j + 1];
                dZ[c] = (gz == 0) ? (zpv - cc)
                                  : ((gz == N - 1) ? (cc - zmv) : 0.5f * (zpv - zmv));
                dX[c] = hx * (RXP[c][j] - RXM[c][j]);
                dY[c] = hy * (RYP[c][j] - RYM[c][j]);
            }
            float igv = igv4[j];
            float lam = fminf(fmaxf(1.0f + 2.0f * igv, 0.1f), 10.0f);
            float mu  = fminf(fmaxf(0.5f + 1.0f * igv, 0.1f), 10.0f);
            float wt  = 1.0f + 5.0f * igv;

            float Exx = dX[0], Eyy = dY[1], Ezz = dZ[2];
            float Exy = 0.5f * (dY[0] + dX[1]);
            float Exz = 0.5f * (dZ[0] + dX[2]);
            float Eyz = 0.5f * (dZ[1] + dY[2]);
            float tr = Exx + Eyy + Ezz;
            float e = 0.5f * lam * tr * tr +
                      mu * (Exx * Exx + Eyy * Eyy + Ezz * Ezz +
                            2.0f * (Exy * Exy + Exz * Exz + Eyz * Eyz));
            lsum += wt * e;
        }
    }
    __shared__ float sm[TPB];
    sm[threadIdx.x] = lsum;
    __syncthreads();
    for (int s = TPB / 2; s > 0; s >>= 1) {
        if (threadIdx.x < s) sm[threadIdx.x] += sm[threadIdx.x + s];
        __syncthreads();
    }
    if (threadIdx.x == 0) partial[blockIdx.x] = sm[0];
}

// -------- combine 3 scale partials + Jacobian penalty -> out[0] --------
__global__ void finalize_kernel(const float* __restrict__ partial,
                                const float* __restrict__ def, float* __restrict__ out) {
    __shared__ float sm[TPB];
    const float wts[3] = {1.0f, 0.5f, 0.25f};
    const float invcnt[3] = {1.0f / (2.0f * 160 * 160 * 160),
                             1.0f / (2.0f * 80 * 80 * 80),
                             1.0f / (2.0f * 40 * 40 * 40)};
    float acc = 0.f;
    for (int s = 0; s < 3; ++s) {
        float local = 0.f;
        for (int i = threadIdx.x; i < RED_NB; i += TPB) local += partial[s * RED_NB + i];
        acc += wts[s] * invcnt[s] * local;
    }
    sm[threadIdx.x] = acc;
    __syncthreads();
    for (int s = TPB / 2; s > 0; s >>= 1) {
        if (threadIdx.x < s) sm[threadIdx.x] += sm[threadIdx.x + s];
        __syncthreads();
    }
    if (threadIdx.x == 0) {
        float jac = 0.f;
        const int n = 160;
        long n3 = (long)n * n * n;
        long ctr = ((long)80 * n + 80) * n + 80;
        for (int b = 0; b < 2; ++b) {
            const float* p = def + (long)b * 3 * n3;
            float J[3][3];
            for (int c = 0; c < 3; ++c) {
                const float* q = p + (long)c * n3 + ctr;
                J[c][0] = 0.5f * (q[(long)n * n] - q[-(long)n * n]);
                J[c][1] = 0.5f * (q[n] - q[-n]);
                J[c][2] = 0.5f * (q[1] - q[-1]);
            }
            float det = J[0][0] * (J[1][1] * J[2][2] - J[1][2] * J[2][1])
                      - J[0][1] * (J[1][0] * J[2][2] - J[1][2] * J[2][0])
                      + J[0][2] * (J[1][0] * J[2][1] - J[1][1] * J[2][0]);
            jac += fmaxf(-det, 0.f);
        }
        jac *= 0.5f; // mean over B=2
        out[0] = sm[0] + 0.1f * jac;
    }
}

extern "C" void kernel_launch(void* const* d_in, const int* in_sizes, int n_in,
                              void* d_out, int out_size, void* d_ws, size_t ws_size,
                              hipStream_t stream) {
    const float* D = (const float*)d_in[0];  // (2,3,160,160,160)
    const float* I = (const float*)d_in[1];  // (2,1,160,160,160)
    float* out = (float*)d_out;
    float* ws = (float*)d_ws;

    float* partials = ws;                  // 3 * RED_NB floats
    float* arena = ws + 3 * RED_NB;

    const int B = 2;
    const long S1 = (long)B * 80 * 80 * 80;
    const long S2 = (long)B * 40 * 40 * 40;

    // disjoint arenas for scales 1 & 2 (scale 0 reuses the whole region afterwards)
    float* ds1 = arena;              // 3*S1
    float* is1 = ds1 + 3 * S1;       // S1
    float* g1  = is1 + S1;           // S1
    float* t1  = g1 + S1;            // S1
    float* ds2 = t1 + S1;            // 3*S2
    float* is2 = ds2 + 3 * S2;       // S2
    float* g2  = is2 + S2;           // S2
    float* t2  = g2 + S2;            // S2

    // ---- all resizes first (D and I each read once; 2nd pass hits L3) ----
    {
        long totD1 = 3 * S1, totD2 = 3 * S2;
        resize3d_kernel<160, 80><<<(int)((totD1 + TPB - 1) / TPB), TPB, 0, stream>>>(D, ds1, B * 3);
        resize3d_kernel<160, 40><<<(int)((totD2 + TPB - 1) / TPB), TPB, 0, stream>>>(D, ds2, B * 3);
        resize3d_kernel<160, 80><<<(int)((S1 + TPB - 1) / TPB), TPB, 0, stream>>>(I, is1, B);
        resize3d_kernel<160, 40><<<(int)((S2 + TPB - 1) / TPB), TPB, 0, stream>>>(I, is2, B);
    }

    // ---- scale 1: n = 80 ----
    {
        long total4 = S1 / 4;
        int blocks = (int)((total4 + TPB - 1) / TPB);
        gradmag_v4<80><<<blocks, TPB, 0, stream>>>(is1, g1, B);
        blur_xy_v4<80, 0><<<blocks, TPB, 0, stream>>>(g1, t1, B);
        blur_xy_v4<80, 1><<<blocks, TPB, 0, stream>>>(t1, g1, B);
        blur_z_v4<80><<<blocks, TPB, 0, stream>>>(g1, t1, B);
        energy_v4<80><<<RED_NB, TPB, 0, stream>>>(ds1, t1, partials + 1 * RED_NB, B);
    }

    // ---- scale 2: n = 40 ----
    {
        long total4 = S2 / 4;
        int blocks = (int)((total4 + TPB - 1) / TPB);
        gradmag_v4<40><<<blocks, TPB, 0, stream>>>(is2, g2, B);
        blur_xy_v4<40, 0><<<blocks, TPB, 0, stream>>>(g2, t2, B);
        blur_xy_v4<40, 1><<<blocks, TPB, 0, stream>>>(t2, g2, B);
        blur_z_v4<40><<<blocks, TPB, 0, stream>>>(g2, t2, B);
        energy_v4<40><<<RED_NB, TPB, 0, stream>>>(ds2, t2, partials + 2 * RED_NB, B);
    }

    // ---- scale 0: n = 160 (identity resize); reuses arena after scales 1-2 done ----
    {
        const long S0 = (long)B * 160 * 160 * 160;
        float* g0 = arena;
        float* t0 = arena + S0;
        long total4 = S0 / 4;
        int blocks = (int)((total4 + TPB - 1) / TPB);
        gradmag_v4<160><<<blocks, TPB, 0, stream>>>(I, g0, B);
        blur_xy_v4<160, 0><<<blocks, TPB, 0, stream>>>(g0, t0, B);
        blur_xy_v4<160, 1><<<blocks, TPB, 0, stream>>>(t0, g0, B);
        blur_z_v4<160><<<blocks, TPB, 0, stream>>>(g0, t0, B);
        energy_v4<160><<<RED_NB, TPB, 0, stream>>>(D, t0, partials + 0 * RED_NB, B);
    }

    finalize_kernel<<<1, TPB, 0, stream>>>(partials, D, out);
}

// Round 5
// 171.047 us; speedup vs baseline: 2.2442x; 1.2381x over previous
//
#include <hip/hip_runtime.h>

#define TPB 256
#define RED_NB 2048

// Gaussian kernel, sigma=1.1, ksize=5 (precomputed, normalized)
#define K0 0.0707663f
#define K1 0.2444606f
#define K2 0.3695462f

typedef float f4 __attribute__((ext_vector_type(4)));

__device__ __forceinline__ f4 ld4(const float* __restrict__ p) { return *(const f4*)p; }

// reflect index (no edge repeat): j<0 -> -j, j>=n -> 2n-2-j
__device__ __forceinline__ int rref(int i, int n) {
    return i < 0 ? -i : (i >= n ? 2 * n - 2 - i : i);
}

// -------- trilinear resize (device helper), align_corners; compile-time sizes --------
template <int NIN, int M>
__device__ __forceinline__ void resize_one(const float* __restrict__ in,
                                           float* __restrict__ out, long idx) {
    constexpr float ratio = (float)((NIN - 1.0) / (M - 1.0));
    int z = (int)(idx % M); long r = idx / M;
    int y = (int)(r % M);   r /= M;
    int x = (int)(r % M);   int bc = (int)(r / M);

    float cx = (float)x * ratio, cy = (float)y * ratio, cz = (float)z * ratio;
    int x0 = min((int)cx, NIN - 1), y0 = min((int)cy, NIN - 1), z0 = min((int)cz, NIN - 1);
    float wx = cx - (float)x0, wy = cy - (float)y0, wz = cz - (float)z0;
    int x1 = min(x0 + 1, NIN - 1), y1 = min(y0 + 1, NIN - 1), z1 = min(z0 + 1, NIN - 1);

    const float* p = in + (long)bc * NIN * NIN * NIN;
    constexpr long sx = (long)NIN * NIN;
#define AT(xi, yi, zi) p[(long)(xi) * sx + (long)(yi) * NIN + (zi)]
    float c00 = AT(x0, y0, z0) * (1.f - wz) + AT(x0, y0, z1) * wz;
    float c01 = AT(x0, y1, z0) * (1.f - wz) + AT(x0, y1, z1) * wz;
    float c10 = AT(x1, y0, z0) * (1.f - wz) + AT(x1, y0, z1) * wz;
    float c11 = AT(x1, y1, z0) * (1.f - wz) + AT(x1, y1, z1) * wz;
#undef AT
    float c0 = c00 * (1.f - wy) + c01 * wy;
    float c1 = c10 * (1.f - wy) + c11 * wy;
    out[idx] = c0 * (1.f - wx) + c1 * wx;
}

// one kernel for all four resizes: ds1(3*S1), ds2(3*S2), is1(S1), is2(S2)
__global__ void resize_all_kernel(const float* __restrict__ D, const float* __restrict__ I,
                                  float* __restrict__ ds1, float* __restrict__ ds2,
                                  float* __restrict__ is1, float* __restrict__ is2,
                                  long A, long Bn, long C, long Dn) {
    long idx = (long)blockIdx.x * blockDim.x + threadIdx.x;
    if (idx < A) { resize_one<160, 80>(D, ds1, idx); return; }
    idx -= A;
    if (idx < Bn) { resize_one<160, 40>(D, ds2, idx); return; }
    idx -= Bn;
    if (idx < C) { resize_one<160, 80>(I, is1, idx); return; }
    idx -= C;
    if (idx < Dn) { resize_one<160, 40>(I, is2, idx); }
}

// -------- gradient magnitude, f4 over z --------
template <int N>
__global__ void gradmag_v4(const float* __restrict__ img, float* __restrict__ g, int B) {
    constexpr int NZ4 = N / 4;
    constexpr long n2 = (long)N * N, n3 = n2 * N;
    long total = (long)B * N * N * NZ4;
    long idx = (long)blockIdx.x * blockDim.x + threadIdx.x;
    if (idx >= total) return;
    int z4 = (int)(idx % NZ4); long r = idx / NZ4;
    int y = (int)(r % N); r /= N;
    int x = (int)(r % N); int b = (int)(r / N);
    int z = z4 * 4;

    const float* base = img + (long)b * n3;
    const float* rowc = base + (long)x * n2 + (long)y * N;
    f4 cur = ld4(rowc + z);
    f4 prev = (z > 0) ? ld4(rowc + z - 4) : cur;
    f4 next = (z + 4 < N) ? ld4(rowc + z + 4) : cur;

    int xm = max(x - 1, 0), xp = min(x + 1, N - 1);
    int ym = max(y - 1, 0), yp = min(y + 1, N - 1);
    float hx = (x == 0 || x == N - 1) ? 1.f : 0.5f;
    float hy = (y == 0 || y == N - 1) ? 1.f : 0.5f;
    f4 rxp = ld4(base + (long)xp * n2 + (long)y * N + z);
    f4 rxm = ld4(base + (long)xm * n2 + (long)y * N + z);
    f4 ryp = ld4(base + (long)x * n2 + (long)yp * N + z);
    f4 rym = ld4(base + (long)x * n2 + (long)ym * N + z);

    f4 outv;
#pragma unroll
    for (int j = 0; j < 4; ++j) {
        float c = cur[j];
        float zmv = (j == 0) ? prev[3] : cur[(j == 0) ? 0 : j - 1];
        float zpv = (j == 3) ? next[0] : cur[(j == 3) ? 3 : j + 1];
        int gz = z + j;
        float dz = (gz == 0) ? (zpv - c) : ((gz == N - 1) ? (c - zmv) : 0.5f * (zpv - zmv));
        float dx = hx * (rxp[j] - rxm[j]);
        float dy = hy * (ryp[j] - rym[j]);
        outv[j] = sqrtf(dx * dx + dy * dy + dz * dz);
    }
    *(f4*)(g + (long)b * n3 + (long)x * n2 + (long)y * N + z) = outv;
}

// -------- fused blur along x AND y (separable, in one pass), f4 over z --------
template <int N>
__global__ void blur_xy_fused_v4(const float* __restrict__ in, float* __restrict__ out, int B) {
    constexpr int NZ4 = N / 4;
    constexpr long n2 = (long)N * N, n3 = n2 * N;
    long total = (long)B * N * N * NZ4;
    long idx = (long)blockIdx.x * blockDim.x + threadIdx.x;
    if (idx >= total) return;
    int z4 = (int)(idx % NZ4); long r = idx / NZ4;
    int y = (int)(r % N); r /= N;
    int x = (int)(r % N); int b = (int)(r / N);
    int z = z4 * 4;

    const float K[5] = {K0, K1, K2, K1, K0};
    const float* base = in + (long)b * n3;
    f4 acc = {0.f, 0.f, 0.f, 0.f};
#pragma unroll
    for (int i = 0; i < 5; ++i) {
        int qx = rref(x + i - 2, N);
        const float* px = base + (long)qx * n2 + z;
        f4 t = {0.f, 0.f, 0.f, 0.f};
#pragma unroll
        for (int j = 0; j < 5; ++j) {
            int qy = rref(y + j - 2, N);
            t += K[j] * ld4(px + (long)qy * N);
        }
        acc += K[i] * t;
    }
    *(f4*)(out + (long)b * n3 + (long)x * n2 + (long)y * N + z) = acc;
}

// -------- Lame strain energy + in-register blur-z of igxy, f4 over z, block-reduced ----
// igxy = blur_x(blur_y(gradmag)); the final z-blur is applied here in registers.
template <int N>
__global__ void energy_v4(const float* __restrict__ def, const float* __restrict__ igxy,
                          float* __restrict__ partial, int B) {
    constexpr int NZ4 = N / 4;
    constexpr long n2 = (long)N * N, n3 = n2 * N;
    long total = (long)B * N * N * NZ4;
    float lsum = 0.f;
    for (long idx = (long)blockIdx.x * blockDim.x + threadIdx.x; idx < total;
         idx += (long)gridDim.x * blockDim.x) {
        int z4 = (int)(idx % NZ4); long r = idx / NZ4;
        int y = (int)(r % N); r /= N;
        int x = (int)(r % N); int b = (int)(r / N);
        int z = z4 * 4;

        int xm = max(x - 1, 0), xp = min(x + 1, N - 1);
        int ym = max(y - 1, 0), yp = min(y + 1, N - 1);
        float hx = (x == 0 || x == N - 1) ? 1.f : 0.5f;
        float hy = (y == 0 || y == N - 1) ? 1.f : 0.5f;

        const float* base = def + (long)b * 3 * n3;
        long sp = (long)x * n2 + (long)y * N + z;

        f4 CC[3], CP[3], CN[3], RXP[3], RXM[3], RYP[3], RYM[3];
#pragma unroll
        for (int c = 0; c < 3; ++c) {
            const float* rc = base + (long)c * n3 + sp;
            CC[c] = ld4(rc);
            CP[c] = (z > 0) ? ld4(rc - 4) : CC[c];
            CN[c] = (z + 4 < N) ? ld4(rc + 4) : CC[c];
            RXP[c] = ld4(base + (long)c * n3 + (long)xp * n2 + (long)y * N + z);
            RXM[c] = ld4(base + (long)c * n3 + (long)xm * n2 + (long)y * N + z);
            RYP[c] = ld4(base + (long)c * n3 + (long)x * n2 + (long)yp * N + z);
            RYM[c] = ld4(base + (long)c * n3 + (long)x * n2 + (long)ym * N + z);
        }

        // z-blur window of igxy (reflect boundary), same pattern as the old blur_z pass
        const float* growc = igxy + (long)b * n3 + (long)x * n2 + (long)y * N;
        f4 gcur = ld4(growc + z);
        f4 gprev, gnext;
        if (z >= 4) gprev = ld4(growc + z - 4);
        else { gprev[0] = growc[4]; gprev[1] = growc[3]; gprev[2] = growc[2]; gprev[3] = growc[1]; }
        if (z + 8 <= N) gnext = ld4(growc + z + 4);
        else { gnext[0] = growc[N - 2]; gnext[1] = growc[N - 3]; gnext[2] = growc[N - 4]; gnext[3] = growc[N - 5]; }
        float gw[12];
#pragma unroll
        for (int i = 0; i < 4; ++i) { gw[i] = gprev[i]; gw[4 + i] = gcur[i]; gw[8 + i] = gnext[i]; }

#pragma unroll
        for (int j = 0; j < 4; ++j) {
            int gz = z + j;
            float dX[3], dY[3], dZ[3];
#pragma unroll
            for (int c = 0; c < 3; ++c) {
                float cc = CC[c][j];
                float zmv = (j == 0) ? CP[c][3] : CC[c][(j == 0) ? 0 : j - 1];
                float zpv = (j == 3) ? CN[c][0] : CC[c][(j == 3) ? 3 : j + 1];
                dZ[c] = (gz == 0) ? (zpv - cc)
                                  : ((gz == N - 1) ? (cc - zmv) : 0.5f * (zpv - zmv));
                dX[c] = hx * (RXP[c][j] - RXM[c][j]);
                dY[c] = hy * (RYP[c][j] - RYM[c][j]);
            }
            float igv = K0 * gw[2 + j] + K1 * gw[3 + j] + K2 * gw[4 + j]
                      + K1 * gw[5 + j] + K0 * gw[6 + j];
            float lam = fminf(fmaxf(1.0f + 2.0f * igv, 0.1f), 10.0f);
            float mu  = fminf(fmaxf(0.5f + 1.0f * igv, 0.1f), 10.0f);
            float wt  = 1.0f + 5.0f * igv;

            float Exx = dX[0], Eyy = dY[1], Ezz = dZ[2];
            float Exy = 0.5f * (dY[0] + dX[1]);
            float Exz = 0.5f * (dZ[0] + dX[2]);
            float Eyz = 0.5f * (dZ[1] + dY[2]);
            float tr = Exx + Eyy + Ezz;
            float e = 0.5f * lam * tr * tr +
                      mu * (Exx * Exx + Eyy * Eyy + Ezz * Ezz +
                            2.0f * (Exy * Exy + Exz * Exz + Eyz * Eyz));
            lsum += wt * e;
        }
    }
    __shared__ float sm[TPB];
    sm[threadIdx.x] = lsum;
    __syncthreads();
    for (int s = TPB / 2; s > 0; s >>= 1) {
        if (threadIdx.x < s) sm[threadIdx.x] += sm[threadIdx.x + s];
        __syncthreads();
    }
    if (threadIdx.x == 0) partial[blockIdx.x] = sm[0];
}

// -------- combine 3 scale partials + Jacobian penalty -> out[0] --------
__global__ void finalize_kernel(const float* __restrict__ partial,
                                const float* __restrict__ def, float* __restrict__ out) {
    __shared__ float sm[TPB];
    const float wts[3] = {1.0f, 0.5f, 0.25f};
    const float invcnt[3] = {1.0f / (2.0f * 160 * 160 * 160),
                             1.0f / (2.0f * 80 * 80 * 80),
                             1.0f / (2.0f * 40 * 40 * 40)};
    float acc = 0.f;
    for (int s = 0; s < 3; ++s) {
        float local = 0.f;
        for (int i = threadIdx.x; i < RED_NB; i += TPB) local += partial[s * RED_NB + i];
        acc += wts[s] * invcnt[s] * local;
    }
    sm[threadIdx.x] = acc;
    __syncthreads();
    for (int s = TPB / 2; s > 0; s >>= 1) {
        if (threadIdx.x < s) sm[threadIdx.x] += sm[threadIdx.x + s];
        __syncthreads();
    }
    if (threadIdx.x == 0) {
        float jac = 0.f;
        const int n = 160;
        long n3 = (long)n * n * n;
        long ctr = ((long)80 * n + 80) * n + 80;
        for (int b = 0; b < 2; ++b) {
            const float* p = def + (long)b * 3 * n3;
            float J[3][3];
            for (int c = 0; c < 3; ++c) {
                const float* q = p + (long)c * n3 + ctr;
                J[c][0] = 0.5f * (q[(long)n * n] - q[-(long)n * n]);
                J[c][1] = 0.5f * (q[n] - q[-n]);
                J[c][2] = 0.5f * (q[1] - q[-1]);
            }
            float det = J[0][0] * (J[1][1] * J[2][2] - J[1][2] * J[2][1])
                      - J[0][1] * (J[1][0] * J[2][2] - J[1][2] * J[2][0])
                      + J[0][2] * (J[1][0] * J[2][1] - J[1][1] * J[2][0]);
            jac += fmaxf(-det, 0.f);
        }
        jac *= 0.5f; // mean over B=2
        out[0] = sm[0] + 0.1f * jac;
    }
}

extern "C" void kernel_launch(void* const* d_in, const int* in_sizes, int n_in,
                              void* d_out, int out_size, void* d_ws, size_t ws_size,
                              hipStream_t stream) {
    const float* D = (const float*)d_in[0];  // (2,3,160,160,160)
    const float* I = (const float*)d_in[1];  // (2,1,160,160,160)
    float* out = (float*)d_out;
    float* ws = (float*)d_ws;

    const int B = 2;
    const long S0 = (long)B * 160 * 160 * 160;
    const long S1 = (long)B * 80 * 80 * 80;
    const long S2 = (long)B * 40 * 40 * 40;

    // disjoint workspace layout
    float* partials = ws;                 // 3 * RED_NB
    float* ds1 = partials + 3 * RED_NB;   // 3*S1
    float* is1 = ds1 + 3 * S1;            // S1
    float* g1  = is1 + S1;                // S1
    float* t1  = g1 + S1;                 // S1
    float* ds2 = t1 + S1;                 // 3*S2
    float* is2 = ds2 + 3 * S2;            // S2
    float* g2  = is2 + S2;                // S2
    float* t2  = g2 + S2;                 // S2
    float* g0  = t2 + S2;                 // S0
    float* t0  = g0 + S0;                 // S0

    // ---- all four resizes in ONE launch (D, I each read once; L3-resident after) ----
    {
        long A = 3 * S1, Bn = 3 * S2, C = S1, Dn = S2;
        long tot = A + Bn + C + Dn;
        resize_all_kernel<<<(int)((tot + TPB - 1) / TPB), TPB, 0, stream>>>(
            D, I, ds1, ds2, is1, is2, A, Bn, C, Dn);
    }

    // ---- scale 0: n=160 (I, D read via L3 after resize) ----
    {
        long total4 = S0 / 4;
        int blocks = (int)((total4 + TPB - 1) / TPB);
        gradmag_v4<160><<<blocks, TPB, 0, stream>>>(I, g0, B);
        blur_xy_fused_v4<160><<<blocks, TPB, 0, stream>>>(g0, t0, B);
        energy_v4<160><<<RED_NB, TPB, 0, stream>>>(D, t0, partials + 0 * RED_NB, B);
    }

    // ---- scale 1: n=80 ----
    {
        long total4 = S1 / 4;
        int blocks = (int)((total4 + TPB - 1) / TPB);
        gradmag_v4<80><<<blocks, TPB, 0, stream>>>(is1, g1, B);
        blur_xy_fused_v4<80><<<blocks, TPB, 0, stream>>>(g1, t1, B);
        energy_v4<80><<<RED_NB, TPB, 0, stream>>>(ds1, t1, partials + 1 * RED_NB, B);
    }

    // ---- scale 2: n=40 ----
    {
        long total4 = S2 / 4;
        int blocks = (int)((total4 + TPB - 1) / TPB);
        gradmag_v4<40><<<blocks, TPB, 0, stream>>>(is2, g2, B);
        blur_xy_fused_v4<40><<<blocks, TPB, 0, stream>>>(g2, t2, B);
        energy_v4<40><<<RED_NB, TPB, 0, stream>>>(ds2, t2, partials + 2 * RED_NB, B);
    }

    finalize_kernel<<<1, TPB, 0, stream>>>(partials, D, out);
}